// Round 6
// baseline (616.163 us; speedup 1.0000x reference)
//
#include <hip/hip_runtime.h>

// HyenaFilter = implicit-filter MLP (tiny) + FFT convolution.
// fftconv (fft_size=16384 >= 2L) == causal linear conv; bias folded into k[0].
// Overlap-add, F=8192 FFTs, 8 pts/thread.
//   y[0:4096)    = inv(K0*Z0)[0:4096)
//   y[4096:8192) = inv(K0*Z0)[4096:) + inv(K0*Z1 + K1*Z0)[0:4096)
// R6: liveness-ordered so only ONE cold spectrum (creg) crosses barriers:
//   Z0->park | K1,C=K1*Z0->creg | K0 | A=K0*Z0, park<-K0 | inv(A), stash
//   A-hi into y-hi | Z1 | B=K0*Z1+C | inv(B) | y-hi += invB.
//   (R5 kept creg+areg cold together -> 869MB scratch at the 64-VGPR cap.)
//   filter_kernel: h[64] moved regs->LDS (same 64-reg spill disease).

#define DIMC  768
#define BANDS 16
#define FO    64
#define LSEQ  8192
#define F8    8192
#define PI_F  3.14159265358979323846f

// bank-decorrelating swizzle for float2 indices (fixes stride-16/8 patterns)
__device__ __forceinline__ int swz(int i) { return i ^ ((i >> 4) & 15); }

// ---------- FFT building blocks (N=8192, 1024 threads, 8 pts/thread) ------
// Ownerships (pos of reg j for thread t):
//   A: j*1024 + t                      (bits 12:10 = j)
//   B: (t>>7)*1024 + j*128 + (t&127)   (bits  9:7 = j)
//   C: (t>>4)*128  + j*16  + (t&15)    (bits  6:4 = j)
//   D: (t>>1)*16   + j*2   + (t&1)     (bits  3:1 = j)
//   E: t*8 + j                         (bit     0 = j0)

template<int SHIFT, int SMAX, int SMIN>
__device__ __forceinline__ void fwd_stages8(float2 (&r)[8], int base)
{
#pragma unroll
    for (int S = SMAX; S >= SMIN; S >>= 1) {
        const int s = S << SHIFT;
        const float scale = -PI_F / (float)s;
#pragma unroll
        for (int g = 0; g < 4; ++g) {
            const int j  = ((g & ~(S - 1)) << 1) | (g & (S - 1));
            const int jS = j + S;
            int wexp = (base + (j << SHIFT)) & (s - 1);
            float ang = scale * (float)wexp;
            float sn, cs;
            __sincosf(ang, &sn, &cs);
            float2 u = r[j], v = r[jS];
            r[j].x = u.x + v.x;
            r[j].y = u.y + v.y;
            float dx = u.x - v.x;
            float dy = u.y - v.y;
            r[jS].x = dx * cs - dy * sn;
            r[jS].y = dx * sn + dy * cs;
        }
    }
}

template<int SHIFT, int SMIN, int SMAX>
__device__ __forceinline__ void inv_stages8(float2 (&r)[8], int base)
{
#pragma unroll
    for (int S = SMIN; S <= SMAX; S <<= 1) {
        const int s = S << SHIFT;
        const float scale = PI_F / (float)s;   // conj twiddle
#pragma unroll
        for (int g = 0; g < 4; ++g) {
            const int j  = ((g & ~(S - 1)) << 1) | (g & (S - 1));
            const int jS = j + S;
            int wexp = (base + (j << SHIFT)) & (s - 1);
            float ang = scale * (float)wexp;
            float sn, cs;
            __sincosf(ang, &sn, &cs);
            float2 u = r[j], v = r[jS];
            float vx = v.x * cs - v.y * sn;
            float vy = v.x * sn + v.y * cs;
            r[j].x  = u.x + vx;
            r[j].y  = u.y + vy;
            r[jS].x = u.x - vx;
            r[jS].y = u.y - vy;
        }
    }
}

__device__ __forceinline__ void xchg8(float2 (&r)[8], float2* xb,
                                      int baseW, int shiftW, int baseR, int shiftR)
{
    __syncthreads();   // WAR vs previous reads of xb
#pragma unroll
    for (int j = 0; j < 8; ++j) xb[swz(baseW + (j << shiftW))] = r[j];
    __syncthreads();
#pragma unroll
    for (int j = 0; j < 8; ++j) r[j] = xb[swz(baseR + (j << shiftR))];
}

// Forward DIF FFT of 8192, input zero-padded: r[0..3] valid, upper half 0.
// Output scrambled, E-ownership.
__device__ __forceinline__ void fft_fwd8(float2 (&r)[8], float2* xb, int t)
{
    const int bA = t;
    const int bB = ((t >> 7) << 10) | (t & 127);
    const int bC = ((t >> 4) << 7)  | (t & 15);
    const int bD = ((t >> 1) << 4)  | (t & 1);
    const int bE = t << 3;
    // stage s=4096 with v=0: lo = u, hi = u * w  (pos = j*1024+t < 4096)
    const float sc0 = -PI_F / 4096.0f;
#pragma unroll
    for (int j = 0; j < 4; ++j) {
        float ang = sc0 * (float)(bA + (j << 10));
        float sn, cs;
        __sincosf(ang, &sn, &cs);
        float2 u = r[j];
        r[j + 4].x = u.x * cs - u.y * sn;
        r[j + 4].y = u.x * sn + u.y * cs;
    }
    fwd_stages8<10, 2, 1>(r, bA);   // s = 2048, 1024
    xchg8(r, xb, bA, 10, bB, 7);
    fwd_stages8<7, 4, 1>(r, bB);    // s = 512, 256, 128
    xchg8(r, xb, bB, 7, bC, 4);
    fwd_stages8<4, 4, 1>(r, bC);    // s = 64, 32, 16
    xchg8(r, xb, bC, 4, bD, 1);
    fwd_stages8<1, 4, 1>(r, bD);    // s = 8, 4, 2
    xchg8(r, xb, bD, 1, bE, 0);
    // s = 1: twiddle = 1
#pragma unroll
    for (int g = 0; g < 4; ++g) {
        const int j = g << 1;
        float2 u = r[j], v = r[j + 1];
        r[j].x = u.x + v.x;   r[j].y = u.y + v.y;
        r[j + 1].x = u.x - v.x; r[j + 1].y = u.y - v.y;
    }
}

// Inverse DIT FFT of 8192: scrambled E-ownership in -> natural A-ownership out.
__device__ __forceinline__ void fft_inv8(float2 (&r)[8], float2* xb, int t)
{
    const int bA = t;
    const int bB = ((t >> 7) << 10) | (t & 127);
    const int bC = ((t >> 4) << 7)  | (t & 15);
    const int bD = ((t >> 1) << 4)  | (t & 1);
    const int bE = t << 3;
    // s = 1: conj twiddle = 1
#pragma unroll
    for (int g = 0; g < 4; ++g) {
        const int j = g << 1;
        float2 u = r[j], v = r[j + 1];
        r[j].x = u.x + v.x;   r[j].y = u.y + v.y;
        r[j + 1].x = u.x - v.x; r[j + 1].y = u.y - v.y;
    }
    xchg8(r, xb, bE, 0, bD, 1);
    inv_stages8<1, 1, 4>(r, bD);    // s = 2, 4, 8
    xchg8(r, xb, bD, 1, bC, 4);
    inv_stages8<4, 1, 4>(r, bC);    // s = 16, 32, 64
    xchg8(r, xb, bC, 4, bB, 7);
    inv_stages8<7, 1, 4>(r, bB);    // s = 128, 256, 512
    xchg8(r, xb, bB, 7, bA, 10);
    inv_stages8<10, 1, 2>(r, bA);   // s = 1024, 2048
    // final stage s = 4096 (pos = j*1024+t < 4096 for j<4)
    const float scF = PI_F / 4096.0f;
#pragma unroll
    for (int j = 0; j < 4; ++j) {
        float ang = scF * (float)(bA + (j << 10));
        float sn, cs;
        __sincosf(ang, &sn, &cs);
        float2 u = r[j], v = r[j + 4];
        float vx = v.x * cs - v.y * sn;
        float vy = v.x * sn + v.y * cs;
        r[j].x = u.x + vx;     r[j].y = u.y + vy;
        r[j + 4].x = u.x - vx; r[j + 4].y = u.y - vy;
    }
}

// ---------- Kernel 1: MLP hidden states h2[FO][LSEQ] ----------------------
__global__ void hidden_kernel(const float* __restrict__ W0, const float* __restrict__ b0,
                              const float* __restrict__ W1, const float* __restrict__ b1,
                              const float* __restrict__ W2, const float* __restrict__ b2,
                              const float* __restrict__ freq, float* __restrict__ hws)
{
    const int lane = threadIdx.x & 63;
    const int p = blockIdx.x * (blockDim.x >> 6) + (threadIdx.x >> 6);
    if (p >= LSEQ) return;
    const float tt = (float)p / (float)(LSEQ - 1);
    const float w  = 6.283185307179586f * (float)p / (float)LSEQ;

    float acc = b0[lane] + tt * W0[lane];
#pragma unroll
    for (int j = 0; j < BANDS; ++j) {
        float f = 1e-4f + (float)j * ((15.0f - 1e-4f) / 15.0f);
        float a = f * w;
        float sn, cs;
        __sincosf(a, &sn, &cs);
        acc += cs  * W0[(1 + j) * FO + lane];
        acc += -sn * W0[(1 + BANDS + j) * FO + lane];
    }
    float h = __sinf(freq[lane] * acc);

    acc = b1[lane];
#pragma unroll
    for (int e = 0; e < FO; ++e) acc += __shfl(h, e) * W1[e * FO + lane];
    float h1 = __sinf(freq[lane] * acc);

    acc = b2[lane];
#pragma unroll
    for (int e = 0; e < FO; ++e) acc += __shfl(h1, e) * W2[e * FO + lane];
    float h2 = __sinf(freq[lane] * acc);

    hws[lane * LSEQ + p] = h2;    // feature-major, coalesced
}

// ---------- Kernel 2: k[d][p] = (h2 . Wf) * (exp(-t|delta|)+0.05) ---------
// h2 tile lives in LDS (h[64] in regs spilled at the 64-VGPR cap).
#define DCHUNK 96
__global__ __launch_bounds__(256)
void filter_kernel(const float* __restrict__ hws, const float* __restrict__ Wf,
                   float* __restrict__ kws)
{
    __shared__ float hsh[256][65];   // stride 65: conflict-free, 66.5 KB
    const int tid = threadIdx.x;
    const int p  = blockIdx.x * 256 + tid;
    const int d0 = blockIdx.y * DCHUNK;
#pragma unroll
    for (int j = 0; j < FO; ++j) hsh[tid][j] = hws[j * LSEQ + p];  // coalesced
    __syncthreads();
    const float tt = (float)p / (float)(LSEQ - 1);
    const float min_decay = -3.0701134573253937f;   // ln(0.01)/1.5
    const float max_decay = -15.350567286626971f;   // ln(0.01)/0.3
    for (int dd = 0; dd < DCHUNK; ++dd) {
        const int d = d0 + dd;
        float acc = 0.f;
#pragma unroll
        for (int j = 0; j < FO; ++j) acc += hsh[tid][j] * Wf[j * DIMC + d];
        float delta = min_decay + (max_decay - min_decay) * ((float)d / (float)(DIMC - 1));
        float dec = __expf(-tt * fabsf(delta));
        kws[(size_t)d * LSEQ + p] = acc * (dec + 0.05f);
    }
}

// ---------- Kernel 3: overlap-add FFT convolution, one block per channel --
__global__ __launch_bounds__(1024)
void conv_kernel(const float* __restrict__ x, const float* __restrict__ kf,
                 const float* __restrict__ bias, float* __restrict__ out)
{
    __shared__ float2 xb[F8];     // 64 KB exchange buffer
    __shared__ float2 park[F8];   // 64 KB spectrum park (thread-private slots)
    const int d = blockIdx.x;
    const int t = threadIdx.x;
    const float invn = 1.0f / 8192.0f;
    const float* x0 = x + (size_t)d * LSEQ;
    const float* x1 = x + (size_t)(DIMC + d) * LSEQ;
    const float* krow = kf + (size_t)d * LSEQ;
    float* o0 = out + (size_t)d * LSEQ;
    float* o1 = out + (size_t)(DIMC + d) * LSEQ;
    float2 r[8];

    // 1. Z0 = FFT(x0[0:4096] + i*x1[0:4096]) -> park
#pragma unroll
    for (int j = 0; j < 4; ++j) { int n = (j << 10) + t; r[j].x = x0[n]; r[j].y = x1[n]; }
    fft_fwd8(r, xb, t);
#pragma unroll
    for (int j = 0; j < 8; ++j) park[swz((t << 3) + j)] = r[j];
    // (no barrier: slots are thread-private; FFT barriers separate anyway)

    // 2. K1 FFT; C = K1*Z0 -> creg (the ONE cold spectrum)
#pragma unroll
    for (int j = 0; j < 4; ++j) { r[j].x = krow[4096 + (j << 10) + t]; r[j].y = 0.f; }
    fft_fwd8(r, xb, t);
    float2 creg[8];
#pragma unroll
    for (int j = 0; j < 8; ++j) {
        int s = swz((t << 3) + j);
        float k1x = r[j].x * invn, k1y = r[j].y * invn;
        float2 z0 = park[s];
        creg[j].x = k1x * z0.x - k1y * z0.y;
        creg[j].y = k1x * z0.y + k1y * z0.x;
    }

    // 3. K0 FFT (bias delta folded: +bias at s=0)
#pragma unroll
    for (int j = 0; j < 4; ++j) { r[j].x = krow[(j << 10) + t]; r[j].y = 0.f; }
    if (t == 0) r[0].x += bias[d];
    fft_fwd8(r, xb, t);

    // 4. A = K0*Z0; park <- K0 (read-then-overwrite own slot)
#pragma unroll
    for (int j = 0; j < 8; ++j) {
        int s = swz((t << 3) + j);
        float k0x = r[j].x * invn, k0y = r[j].y * invn;
        float2 z0 = park[s];
        park[s] = make_float2(k0x, k0y);
        r[j].x = k0x * z0.x - k0y * z0.y;
        r[j].y = k0x * z0.y + k0y * z0.x;
    }

    // 5. inv(A): y-lo final; A-hi stashed into y-hi (added to later)
    fft_inv8(r, xb, t);
#pragma unroll
    for (int j = 0; j < 4; ++j) {
        int n = (j << 10) + t;
        o0[n] = r[j].x;
        o1[n] = r[j].y;
    }
#pragma unroll
    for (int j = 0; j < 4; ++j) {
        int n = 4096 + (j << 10) + t;
        o0[n] = r[j + 4].x;
        o1[n] = r[j + 4].y;
    }

    // 6. Z1 = FFT(x[4096:8192] packed)
#pragma unroll
    for (int j = 0; j < 4; ++j) { int n = 4096 + (j << 10) + t; r[j].x = x0[n]; r[j].y = x1[n]; }
    fft_fwd8(r, xb, t);

    // 7. B = K0(park)*Z1 + C   (creg dies here)
#pragma unroll
    for (int j = 0; j < 8; ++j) {
        int s = swz((t << 3) + j);
        float2 k0 = park[s];
        float2 z  = r[j];
        r[j].x = k0.x * z.x - k0.y * z.y + creg[j].x;
        r[j].y = k0.x * z.y + k0.y * z.x + creg[j].y;
    }

    // 8. inv(B); 9. y-hi += invB-lo (same-thread RMW of the stash)
    fft_inv8(r, xb, t);
#pragma unroll
    for (int j = 0; j < 4; ++j) {
        int n = 4096 + (j << 10) + t;
        o0[n] += r[j].x;
        o1[n] += r[j].y;
    }
}

extern "C" void kernel_launch(void* const* d_in, const int* in_sizes, int n_in,
                              void* d_out, int out_size, void* d_ws, size_t ws_size,
                              hipStream_t stream)
{
    (void)in_sizes; (void)n_in; (void)out_size; (void)d_ws; (void)ws_size;
    const float* x    = (const float*)d_in[0];
    const float* W0   = (const float*)d_in[1];
    const float* b0   = (const float*)d_in[2];
    const float* W1   = (const float*)d_in[3];
    const float* b1   = (const float*)d_in[4];
    const float* W2   = (const float*)d_in[5];
    const float* b2   = (const float*)d_in[6];
    const float* Wf   = (const float*)d_in[7];
    const float* freq = (const float*)d_in[8];
    const float* bias = (const float*)d_in[9];
    float* out = (float*)d_out;

    // Scratch staged inside d_out (block d reads its own k row fully before
    // its first write lands there — first o1 write is step 5):
    float* hws = out;                            // h2[64][8192] (2 MB)
    float* kws = out + (size_t)DIMC * LSEQ;      // k[768][8192] (25 MB)

    hipLaunchKernelGGL(hidden_kernel, dim3(LSEQ / 4), dim3(256), 0, stream,
                       W0, b0, W1, b1, W2, b2, freq, hws);
    hipLaunchKernelGGL(filter_kernel, dim3(LSEQ / 256, DIMC / DCHUNK), dim3(256), 0, stream,
                       hws, Wf, kws);
    hipLaunchKernelGGL(conv_kernel, dim3(DIMC), dim3(1024), 0, stream,
                       x, kws, bias, out);
}

// Round 7
// 610.246 us; speedup vs baseline: 1.0097x; 1.0097x over previous
//
#include <hip/hip_runtime.h>

// HyenaFilter = implicit-filter MLP (tiny) + FFT convolution.
// fftconv (fft_size=16384 >= 2L) == causal linear conv; bias folded into k[0].
// Overlap-add, F=8192 FFTs, 8 pts/thread.
//   y[0:4096)    = inv(K0*Z0)[0:4096)
//   y[4096:8192) = inv(K0*Z0)[4096:) + inv(K0*Z1 + K1*Z0)[0:4096)
// R7: __sincosf is an OCML *call* (pointer out-arg) -> caller-save ABI
//     (VGPR pinned 64/SGPR 112 in R1-R6) + spill of all live FFT state
//     around ~290 call sites/thread = the ~1GB scratch traffic. Replaced
//     with value-returning inline __sinf/__cosf (v_fract+v_sin_f32).

#define DIMC  768
#define BANDS 16
#define FO    64
#define LSEQ  8192
#define F8    8192
#define PI_F  3.14159265358979323846f

// bank-decorrelating swizzle for float2 indices (fixes stride-16/8 patterns)
__device__ __forceinline__ int swz(int i) { return i ^ ((i >> 4) & 15); }

// inline twiddle: sn = sin(ang), cs = cos(ang); ang in radians, value-returning
__device__ __forceinline__ void tw(float ang, float& sn, float& cs)
{
    sn = __sinf(ang);
    cs = __cosf(ang);
}

// ---------- FFT building blocks (N=8192, 1024 threads, 8 pts/thread) ------
// Ownerships (pos of reg j for thread t):
//   A: j*1024 + t                      (bits 12:10 = j)
//   B: (t>>7)*1024 + j*128 + (t&127)   (bits  9:7 = j)
//   C: (t>>4)*128  + j*16  + (t&15)    (bits  6:4 = j)
//   D: (t>>1)*16   + j*2   + (t&1)     (bits  3:1 = j)
//   E: t*8 + j                         (bit     0 = j0)

template<int SHIFT, int SMAX, int SMIN>
__device__ __forceinline__ void fwd_stages8(float2 (&r)[8], int base)
{
#pragma unroll
    for (int S = SMAX; S >= SMIN; S >>= 1) {
        const int s = S << SHIFT;
        const float scale = -PI_F / (float)s;
#pragma unroll
        for (int g = 0; g < 4; ++g) {
            const int j  = ((g & ~(S - 1)) << 1) | (g & (S - 1));
            const int jS = j + S;
            int wexp = (base + (j << SHIFT)) & (s - 1);
            float ang = scale * (float)wexp;
            float sn, cs;
            tw(ang, sn, cs);
            float2 u = r[j], v = r[jS];
            r[j].x = u.x + v.x;
            r[j].y = u.y + v.y;
            float dx = u.x - v.x;
            float dy = u.y - v.y;
            r[jS].x = dx * cs - dy * sn;
            r[jS].y = dx * sn + dy * cs;
        }
    }
}

template<int SHIFT, int SMIN, int SMAX>
__device__ __forceinline__ void inv_stages8(float2 (&r)[8], int base)
{
#pragma unroll
    for (int S = SMIN; S <= SMAX; S <<= 1) {
        const int s = S << SHIFT;
        const float scale = PI_F / (float)s;   // conj twiddle
#pragma unroll
        for (int g = 0; g < 4; ++g) {
            const int j  = ((g & ~(S - 1)) << 1) | (g & (S - 1));
            const int jS = j + S;
            int wexp = (base + (j << SHIFT)) & (s - 1);
            float ang = scale * (float)wexp;
            float sn, cs;
            tw(ang, sn, cs);
            float2 u = r[j], v = r[jS];
            float vx = v.x * cs - v.y * sn;
            float vy = v.x * sn + v.y * cs;
            r[j].x  = u.x + vx;
            r[j].y  = u.y + vy;
            r[jS].x = u.x - vx;
            r[jS].y = u.y - vy;
        }
    }
}

__device__ __forceinline__ void xchg8(float2 (&r)[8], float2* xb,
                                      int baseW, int shiftW, int baseR, int shiftR)
{
    __syncthreads();   // WAR vs previous reads of xb
#pragma unroll
    for (int j = 0; j < 8; ++j) xb[swz(baseW + (j << shiftW))] = r[j];
    __syncthreads();
#pragma unroll
    for (int j = 0; j < 8; ++j) r[j] = xb[swz(baseR + (j << shiftR))];
}

// Forward DIF FFT of 8192, input zero-padded: r[0..3] valid, upper half 0.
// Output scrambled, E-ownership.
__device__ __forceinline__ void fft_fwd8(float2 (&r)[8], float2* xb, int t)
{
    const int bA = t;
    const int bB = ((t >> 7) << 10) | (t & 127);
    const int bC = ((t >> 4) << 7)  | (t & 15);
    const int bD = ((t >> 1) << 4)  | (t & 1);
    const int bE = t << 3;
    // stage s=4096 with v=0: lo = u, hi = u * w  (pos = j*1024+t < 4096)
    const float sc0 = -PI_F / 4096.0f;
#pragma unroll
    for (int j = 0; j < 4; ++j) {
        float ang = sc0 * (float)(bA + (j << 10));
        float sn, cs;
        tw(ang, sn, cs);
        float2 u = r[j];
        r[j + 4].x = u.x * cs - u.y * sn;
        r[j + 4].y = u.x * sn + u.y * cs;
    }
    fwd_stages8<10, 2, 1>(r, bA);   // s = 2048, 1024
    xchg8(r, xb, bA, 10, bB, 7);
    fwd_stages8<7, 4, 1>(r, bB);    // s = 512, 256, 128
    xchg8(r, xb, bB, 7, bC, 4);
    fwd_stages8<4, 4, 1>(r, bC);    // s = 64, 32, 16
    xchg8(r, xb, bC, 4, bD, 1);
    fwd_stages8<1, 4, 1>(r, bD);    // s = 8, 4, 2
    xchg8(r, xb, bD, 1, bE, 0);
    // s = 1: twiddle = 1
#pragma unroll
    for (int g = 0; g < 4; ++g) {
        const int j = g << 1;
        float2 u = r[j], v = r[j + 1];
        r[j].x = u.x + v.x;   r[j].y = u.y + v.y;
        r[j + 1].x = u.x - v.x; r[j + 1].y = u.y - v.y;
    }
}

// Inverse DIT FFT of 8192: scrambled E-ownership in -> natural A-ownership out.
__device__ __forceinline__ void fft_inv8(float2 (&r)[8], float2* xb, int t)
{
    const int bA = t;
    const int bB = ((t >> 7) << 10) | (t & 127);
    const int bC = ((t >> 4) << 7)  | (t & 15);
    const int bD = ((t >> 1) << 4)  | (t & 1);
    const int bE = t << 3;
    // s = 1: conj twiddle = 1
#pragma unroll
    for (int g = 0; g < 4; ++g) {
        const int j = g << 1;
        float2 u = r[j], v = r[j + 1];
        r[j].x = u.x + v.x;   r[j].y = u.y + v.y;
        r[j + 1].x = u.x - v.x; r[j + 1].y = u.y - v.y;
    }
    xchg8(r, xb, bE, 0, bD, 1);
    inv_stages8<1, 1, 4>(r, bD);    // s = 2, 4, 8
    xchg8(r, xb, bD, 1, bC, 4);
    inv_stages8<4, 1, 4>(r, bC);    // s = 16, 32, 64
    xchg8(r, xb, bC, 4, bB, 7);
    inv_stages8<7, 1, 4>(r, bB);    // s = 128, 256, 512
    xchg8(r, xb, bB, 7, bA, 10);
    inv_stages8<10, 1, 2>(r, bA);   // s = 1024, 2048
    // final stage s = 4096 (pos = j*1024+t < 4096 for j<4)
    const float scF = PI_F / 4096.0f;
#pragma unroll
    for (int j = 0; j < 4; ++j) {
        float ang = scF * (float)(bA + (j << 10));
        float sn, cs;
        tw(ang, sn, cs);
        float2 u = r[j], v = r[j + 4];
        float vx = v.x * cs - v.y * sn;
        float vy = v.x * sn + v.y * cs;
        r[j].x = u.x + vx;     r[j].y = u.y + vy;
        r[j + 4].x = u.x - vx; r[j + 4].y = u.y - vy;
    }
}

// ---------- Kernel 1: MLP hidden states h2[FO][LSEQ] ----------------------
__global__ void hidden_kernel(const float* __restrict__ W0, const float* __restrict__ b0,
                              const float* __restrict__ W1, const float* __restrict__ b1,
                              const float* __restrict__ W2, const float* __restrict__ b2,
                              const float* __restrict__ freq, float* __restrict__ hws)
{
    const int lane = threadIdx.x & 63;
    const int p = blockIdx.x * (blockDim.x >> 6) + (threadIdx.x >> 6);
    if (p >= LSEQ) return;
    const float tt = (float)p / (float)(LSEQ - 1);
    const float w  = 6.283185307179586f * (float)p / (float)LSEQ;

    float acc = b0[lane] + tt * W0[lane];
#pragma unroll
    for (int j = 0; j < BANDS; ++j) {
        float f = 1e-4f + (float)j * ((15.0f - 1e-4f) / 15.0f);
        float a = f * w;
        acc += __cosf(a)  * W0[(1 + j) * FO + lane];
        acc += -__sinf(a) * W0[(1 + BANDS + j) * FO + lane];
    }
    float h = __sinf(freq[lane] * acc);

    acc = b1[lane];
#pragma unroll
    for (int e = 0; e < FO; ++e) acc += __shfl(h, e) * W1[e * FO + lane];
    float h1 = __sinf(freq[lane] * acc);

    acc = b2[lane];
#pragma unroll
    for (int e = 0; e < FO; ++e) acc += __shfl(h1, e) * W2[e * FO + lane];
    float h2 = __sinf(freq[lane] * acc);

    hws[lane * LSEQ + p] = h2;    // feature-major, coalesced
}

// ---------- Kernel 2: k[d][p] = (h2 . Wf) * (exp(-t|delta|)+0.05) ---------
// h2 tile lives in LDS.
#define DCHUNK 96
__global__ __launch_bounds__(256)
void filter_kernel(const float* __restrict__ hws, const float* __restrict__ Wf,
                   float* __restrict__ kws)
{
    __shared__ float hsh[256][65];   // stride 65: conflict-free, 66.5 KB
    const int tid = threadIdx.x;
    const int p  = blockIdx.x * 256 + tid;
    const int d0 = blockIdx.y * DCHUNK;
#pragma unroll
    for (int j = 0; j < FO; ++j) hsh[tid][j] = hws[j * LSEQ + p];  // coalesced
    __syncthreads();
    const float tt = (float)p / (float)(LSEQ - 1);
    const float min_decay = -3.0701134573253937f;   // ln(0.01)/1.5
    const float max_decay = -15.350567286626971f;   // ln(0.01)/0.3
    for (int dd = 0; dd < DCHUNK; ++dd) {
        const int d = d0 + dd;
        float acc = 0.f;
#pragma unroll
        for (int j = 0; j < FO; ++j) acc += hsh[tid][j] * Wf[j * DIMC + d];
        float delta = min_decay + (max_decay - min_decay) * ((float)d / (float)(DIMC - 1));
        float dec = __expf(-tt * fabsf(delta));
        kws[(size_t)d * LSEQ + p] = acc * (dec + 0.05f);
    }
}

// ---------- Kernel 3: overlap-add FFT convolution, one block per channel --
__global__ __launch_bounds__(1024)
void conv_kernel(const float* __restrict__ x, const float* __restrict__ kf,
                 const float* __restrict__ bias, float* __restrict__ out)
{
    __shared__ float2 xb[F8];     // 64 KB exchange buffer
    __shared__ float2 park[F8];   // 64 KB spectrum park (thread-private slots)
    const int d = blockIdx.x;
    const int t = threadIdx.x;
    const float invn = 1.0f / 8192.0f;
    const float* x0 = x + (size_t)d * LSEQ;
    const float* x1 = x + (size_t)(DIMC + d) * LSEQ;
    const float* krow = kf + (size_t)d * LSEQ;
    float* o0 = out + (size_t)d * LSEQ;
    float* o1 = out + (size_t)(DIMC + d) * LSEQ;
    float2 r[8];

    // 1. Z0 = FFT(x0[0:4096] + i*x1[0:4096]) -> park
#pragma unroll
    for (int j = 0; j < 4; ++j) { int n = (j << 10) + t; r[j].x = x0[n]; r[j].y = x1[n]; }
    fft_fwd8(r, xb, t);
#pragma unroll
    for (int j = 0; j < 8; ++j) park[swz((t << 3) + j)] = r[j];
    // (no barrier: slots are thread-private; FFT barriers separate anyway)

    // 2. K1 FFT; C = K1*Z0 -> creg (the ONE cold spectrum)
#pragma unroll
    for (int j = 0; j < 4; ++j) { r[j].x = krow[4096 + (j << 10) + t]; r[j].y = 0.f; }
    fft_fwd8(r, xb, t);
    float2 creg[8];
#pragma unroll
    for (int j = 0; j < 8; ++j) {
        int s = swz((t << 3) + j);
        float k1x = r[j].x * invn, k1y = r[j].y * invn;
        float2 z0 = park[s];
        creg[j].x = k1x * z0.x - k1y * z0.y;
        creg[j].y = k1x * z0.y + k1y * z0.x;
    }

    // 3. K0 FFT (bias delta folded: +bias at s=0)
#pragma unroll
    for (int j = 0; j < 4; ++j) { r[j].x = krow[(j << 10) + t]; r[j].y = 0.f; }
    if (t == 0) r[0].x += bias[d];
    fft_fwd8(r, xb, t);

    // 4. A = K0*Z0; park <- K0 (read-then-overwrite own slot)
#pragma unroll
    for (int j = 0; j < 8; ++j) {
        int s = swz((t << 3) + j);
        float k0x = r[j].x * invn, k0y = r[j].y * invn;
        float2 z0 = park[s];
        park[s] = make_float2(k0x, k0y);
        r[j].x = k0x * z0.x - k0y * z0.y;
        r[j].y = k0x * z0.y + k0y * z0.x;
    }

    // 5. inv(A): y-lo final; A-hi stashed into y-hi (added to later)
    fft_inv8(r, xb, t);
#pragma unroll
    for (int j = 0; j < 4; ++j) {
        int n = (j << 10) + t;
        o0[n] = r[j].x;
        o1[n] = r[j].y;
    }
#pragma unroll
    for (int j = 0; j < 4; ++j) {
        int n = 4096 + (j << 10) + t;
        o0[n] = r[j + 4].x;
        o1[n] = r[j + 4].y;
    }

    // 6. Z1 = FFT(x[4096:8192] packed)
#pragma unroll
    for (int j = 0; j < 4; ++j) { int n = 4096 + (j << 10) + t; r[j].x = x0[n]; r[j].y = x1[n]; }
    fft_fwd8(r, xb, t);

    // 7. B = K0(park)*Z1 + C   (creg dies here)
#pragma unroll
    for (int j = 0; j < 8; ++j) {
        int s = swz((t << 3) + j);
        float2 k0 = park[s];
        float2 z  = r[j];
        r[j].x = k0.x * z.x - k0.y * z.y + creg[j].x;
        r[j].y = k0.x * z.y + k0.y * z.x + creg[j].y;
    }

    // 8. inv(B); 9. y-hi += invB-lo (same-thread RMW of the stash)
    fft_inv8(r, xb, t);
#pragma unroll
    for (int j = 0; j < 4; ++j) {
        int n = 4096 + (j << 10) + t;
        o0[n] += r[j].x;
        o1[n] += r[j].y;
    }
}

extern "C" void kernel_launch(void* const* d_in, const int* in_sizes, int n_in,
                              void* d_out, int out_size, void* d_ws, size_t ws_size,
                              hipStream_t stream)
{
    (void)in_sizes; (void)n_in; (void)out_size; (void)d_ws; (void)ws_size;
    const float* x    = (const float*)d_in[0];
    const float* W0   = (const float*)d_in[1];
    const float* b0   = (const float*)d_in[2];
    const float* W1   = (const float*)d_in[3];
    const float* b1   = (const float*)d_in[4];
    const float* W2   = (const float*)d_in[5];
    const float* b2   = (const float*)d_in[6];
    const float* Wf   = (const float*)d_in[7];
    const float* freq = (const float*)d_in[8];
    const float* bias = (const float*)d_in[9];
    float* out = (float*)d_out;

    // Scratch staged inside d_out (block d reads its own k row fully before
    // its first write lands there — first o1 write is step 5):
    float* hws = out;                            // h2[64][8192] (2 MB)
    float* kws = out + (size_t)DIMC * LSEQ;      // k[768][8192] (25 MB)

    hipLaunchKernelGGL(hidden_kernel, dim3(LSEQ / 4), dim3(256), 0, stream,
                       W0, b0, W1, b1, W2, b2, freq, hws);
    hipLaunchKernelGGL(filter_kernel, dim3(LSEQ / 256, DIMC / DCHUNK), dim3(256), 0, stream,
                       hws, Wf, kws);
    hipLaunchKernelGGL(conv_kernel, dim3(DIMC), dim3(1024), 0, stream,
                       x, kws, bias, out);
}

// Round 9
// 320.057 us; speedup vs baseline: 1.9252x; 1.9067x over previous
//
#include <hip/hip_runtime.h>
#include <hip/hip_fp16.h>

// HyenaFilter = implicit-filter MLP (tiny) + FFT convolution.
// fftconv (fft_size=16384 >= 2L) == causal linear conv; bias folded into k[0].
// R8: LDS-resident radix-4 FFT (7 stages, N=16384), butterflies on NAMED
//     SCALARS — no per-thread arrays anywhere (R1-R7's ~1GB HBM traffic
//     tracked per-thread float2[] access count => SROA failure/scratch).
// R9: fix R8's double normalization — unnormalized radix-4 inverse yields
//     N*x (4^7=16384), so exactly ONE 1/N is needed (kept in kfft only).
//     R8 applied it again in conv's multiply -> outputs/16384 ~ 0.

#define DIMC  768
#define BANDS 16
#define FO    64
#define LSEQ  8192
#define NF    16384
#define PI_F  3.14159265358979323846f

// bank-decorrelating swizzle for float2 LDS indices
__device__ __forceinline__ int swz(int i) { return i ^ ((i >> 4) & 15); }

// x * (c - i s)   [forward twiddle]
__device__ __forceinline__ float2 cmulm(float xr, float xi, float c, float s) {
    return make_float2(xr * c + xi * s, xi * c - xr * s);
}
// x * (c + i s)   [inverse twiddle]
__device__ __forceinline__ float2 cmulp(float xr, float xi, float c, float s) {
    return make_float2(xr * c - xi * s, xi * c + xr * s);
}

// ---- forward DIF radix-4 stage, quarter-stride S = 1<<SH -----------------
template<int SH>
__device__ __forceinline__ void fwd_stage(float2* L, int t)
{
    __syncthreads();
    const int S = 1 << SH;
#pragma unroll
    for (int m = 0; m < 4; ++m) {
        int b = t + (m << 10);
        int q = b & (S - 1);
        int p = ((b >> SH) << (SH + 2)) + q;
        float2 U0 = L[swz(p)];
        float2 U1 = L[swz(p + S)];
        float2 U2 = L[swz(p + 2 * S)];
        float2 U3 = L[swz(p + 3 * S)];
        float th = (float)q * (PI_F / (2.0f * (float)S));
        float c1 = __cosf(th), s1 = __sinf(th);
        float c2 = c1 * c1 - s1 * s1, s2 = 2.0f * c1 * s1;
        float c3 = c1 * c2 - s1 * s2, s3 = c1 * s2 + s1 * c2;
        float Ar = U0.x + U2.x, Ai = U0.y + U2.y;
        float Br = U0.x - U2.x, Bi = U0.y - U2.y;
        float Cr = U1.x + U3.x, Ci = U1.y + U3.y;
        float Dr = U1.y - U3.y, Di = U3.x - U1.x;     // D = -i(u1-u3)
        L[swz(p)]         = make_float2(Ar + Cr, Ai + Ci);
        L[swz(p + S)]     = cmulm(Br + Dr, Bi + Di, c1, s1);
        L[swz(p + 2 * S)] = cmulm(Ar - Cr, Ai - Ci, c2, s2);
        L[swz(p + 3 * S)] = cmulm(Br - Dr, Bi - Di, c3, s3);
    }
}

// first forward stage (S=4096) with zero-padded input: u2 = u3 = 0.
// Upper half of LDS is never read; it is fully written here.
__device__ __forceinline__ void fwd_stage_zp(float2* L, int t)
{
    __syncthreads();
#pragma unroll
    for (int m = 0; m < 4; ++m) {
        int b = t + (m << 10);
        float2 U0 = L[swz(b)];
        float2 U1 = L[swz(b + 4096)];
        float th = (float)b * (PI_F / 8192.0f);
        float c1 = __cosf(th), s1 = __sinf(th);
        float c2 = c1 * c1 - s1 * s1, s2 = 2.0f * c1 * s1;
        float c3 = c1 * c2 - s1 * s2, s3 = c1 * s2 + s1 * c2;
        // A=B=U0, C=U1, D=-i*U1=(U1.y, -U1.x)
        L[swz(b)]         = make_float2(U0.x + U1.x, U0.y + U1.y);
        L[swz(b + 4096)]  = cmulm(U0.x + U1.y, U0.y - U1.x, c1, s1);
        L[swz(b + 8192)]  = cmulm(U0.x - U1.x, U0.y - U1.y, c2, s2);
        L[swz(b + 12288)] = cmulm(U0.x - U1.y, U0.y + U1.x, c3, s3);
    }
}

// ---- inverse DIT radix-4 stage (consumes scrambled, conj twiddles) -------
template<int SH>
__device__ __forceinline__ void inv_stage(float2* L, int t)
{
    __syncthreads();
    const int S = 1 << SH;
#pragma unroll
    for (int m = 0; m < 4; ++m) {
        int b = t + (m << 10);
        int q = b & (S - 1);
        int p = ((b >> SH) << (SH + 2)) + q;
        float2 V0 = L[swz(p)];
        float2 V1 = L[swz(p + S)];
        float2 V2 = L[swz(p + 2 * S)];
        float2 V3 = L[swz(p + 3 * S)];
        float th = (float)q * (PI_F / (2.0f * (float)S));
        float c1 = __cosf(th), s1 = __sinf(th);
        float c2 = c1 * c1 - s1 * s1, s2 = 2.0f * c1 * s1;
        float c3 = c1 * c2 - s1 * s2, s3 = c1 * s2 + s1 * c2;
        V1 = cmulp(V1.x, V1.y, c1, s1);
        V2 = cmulp(V2.x, V2.y, c2, s2);
        V3 = cmulp(V3.x, V3.y, c3, s3);
        float e0r = V0.x + V2.x, e0i = V0.y + V2.y;
        float e1r = V0.x - V2.x, e1i = V0.y - V2.y;
        float f0r = V1.x + V3.x, f0i = V1.y + V3.y;
        float f1r = V1.x - V3.x, f1i = V1.y - V3.y;   // i*f1 = (-f1i, f1r)
        L[swz(p)]         = make_float2(e0r + f0r, e0i + f0i);
        L[swz(p + S)]     = make_float2(e1r - f1i, e1i + f1r);
        L[swz(p + 2 * S)] = make_float2(e0r - f0r, e0i - f0i);
        L[swz(p + 3 * S)] = make_float2(e1r + f1i, e1i - f1r);
    }
}

// last inverse stage (S=4096), truncated: only outputs n < 8192 are needed.
__device__ __forceinline__ void inv_stage_last(float2* L, int t)
{
    __syncthreads();
#pragma unroll
    for (int m = 0; m < 4; ++m) {
        int b = t + (m << 10);     // p = q = b
        float2 V0 = L[swz(b)];
        float2 V1 = L[swz(b + 4096)];
        float2 V2 = L[swz(b + 8192)];
        float2 V3 = L[swz(b + 12288)];
        float th = (float)b * (PI_F / 8192.0f);
        float c1 = __cosf(th), s1 = __sinf(th);
        float c2 = c1 * c1 - s1 * s1, s2 = 2.0f * c1 * s1;
        float c3 = c1 * c2 - s1 * s2, s3 = c1 * s2 + s1 * c2;
        V1 = cmulp(V1.x, V1.y, c1, s1);
        V2 = cmulp(V2.x, V2.y, c2, s2);
        V3 = cmulp(V3.x, V3.y, c3, s3);
        float e1r = V0.x - V2.x, e1i = V0.y - V2.y;
        float f1r = V1.x - V3.x, f1i = V1.y - V3.y;
        L[swz(b)]        = make_float2(V0.x + V2.x + V1.x + V3.x,
                                       V0.y + V2.y + V1.y + V3.y);
        L[swz(b + 4096)] = make_float2(e1r - f1i, e1i + f1r);
    }
}

#define FWD_ALL(L, t)  do { fwd_stage_zp(L, t); fwd_stage<10>(L, t); \
    fwd_stage<8>(L, t); fwd_stage<6>(L, t); fwd_stage<4>(L, t); \
    fwd_stage<2>(L, t); fwd_stage<0>(L, t); } while (0)

// ---------- Kernel 1: MLP hidden states h2[FO][LSEQ] ----------------------
__global__ void hidden_kernel(const float* __restrict__ W0, const float* __restrict__ b0,
                              const float* __restrict__ W1, const float* __restrict__ b1,
                              const float* __restrict__ W2, const float* __restrict__ b2,
                              const float* __restrict__ freq, float* __restrict__ hws)
{
    const int lane = threadIdx.x & 63;
    const int p = blockIdx.x * (blockDim.x >> 6) + (threadIdx.x >> 6);
    if (p >= LSEQ) return;
    const float tt = (float)p / (float)(LSEQ - 1);
    const float w  = 6.283185307179586f * (float)p / (float)LSEQ;

    float acc = b0[lane] + tt * W0[lane];
#pragma unroll
    for (int j = 0; j < BANDS; ++j) {
        float f = 1e-4f + (float)j * ((15.0f - 1e-4f) / 15.0f);
        float a = f * w;
        acc += __cosf(a)  * W0[(1 + j) * FO + lane];
        acc += -__sinf(a) * W0[(1 + BANDS + j) * FO + lane];
    }
    float h = __sinf(freq[lane] * acc);

    acc = b1[lane];
#pragma unroll
    for (int e = 0; e < FO; ++e) acc += __shfl(h, e) * W1[e * FO + lane];
    float h1 = __sinf(freq[lane] * acc);

    acc = b2[lane];
#pragma unroll
    for (int e = 0; e < FO; ++e) acc += __shfl(h1, e) * W2[e * FO + lane];
    float h2 = __sinf(freq[lane] * acc);

    hws[lane * LSEQ + p] = h2;    // feature-major, coalesced
}

// ---------- Kernel 2: k[d][p] = (h2 . Wf) * (exp(-t|delta|)+0.05) ---------
#define DCHUNK 96
__global__ __launch_bounds__(256)
void filter_kernel(const float* __restrict__ hws, const float* __restrict__ Wf,
                   float* __restrict__ kws)
{
    __shared__ float hsh[256][65];   // stride 65: conflict-free
    const int tid = threadIdx.x;
    const int p  = blockIdx.x * 256 + tid;
    const int d0 = blockIdx.y * DCHUNK;
#pragma unroll
    for (int j = 0; j < FO; ++j) hsh[tid][j] = hws[j * LSEQ + p];  // coalesced
    __syncthreads();
    const float tt = (float)p / (float)(LSEQ - 1);
    const float min_decay = -3.0701134573253937f;   // ln(0.01)/1.5
    const float max_decay = -15.350567286626971f;   // ln(0.01)/0.3
    for (int dd = 0; dd < DCHUNK; ++dd) {
        const int d = d0 + dd;
        float acc = 0.f;
#pragma unroll
        for (int j = 0; j < FO; ++j) acc += hsh[tid][j] * Wf[j * DIMC + d];
        float delta = min_decay + (max_decay - min_decay) * ((float)d / (float)(DIMC - 1));
        float dec = __expf(-tt * fabsf(delta));
        kws[(size_t)d * LSEQ + p] = acc * (dec + 0.05f);
    }
}

// ---------- Kernel 3: K-hat = FFT(k)/N per channel ------------------------
// MODE 0: fp32 into d_ws. MODE 1: half2 overlaid on out rows (d, DIMC+d),
// which this block fully reads (kws row d == out row DIMC+d) before writing.
template<int MODE>
__global__ __launch_bounds__(1024)
void kfft_kernel(const float* __restrict__ kf, const float* __restrict__ bias,
                 float2* __restrict__ KF, float* __restrict__ outbase)
{
    __shared__ float2 L[NF];
    const int d = blockIdx.x, t = threadIdx.x;
    const float* krow = kf + (size_t)d * LSEQ;
#pragma unroll
    for (int j = 0; j < 8; ++j) {
        int n = t + (j << 10);
        float v = krow[n];
        if (n == 0) v += bias[d];          // delta at s=0 == +bias*u term
        L[swz(n)] = make_float2(v, 0.f);
    }
    FWD_ALL(L, t);
    __syncthreads();
    const float invn = 1.0f / 16384.0f;    // the ONLY 1/N in the pipeline
    if (MODE == 0) {
        float2* Kd = KF + (size_t)d * NF;
#pragma unroll
        for (int j = 0; j < 16; ++j) {
            int i = t + (j << 10);
            float2 v = L[swz(i)];
            Kd[i] = make_float2(v.x * invn, v.y * invn);
        }
    } else {
        __half2* H0 = (__half2*)(outbase + (size_t)d * LSEQ);
        __half2* H1 = (__half2*)(outbase + (size_t)(DIMC + d) * LSEQ);
#pragma unroll
        for (int j = 0; j < 16; ++j) {
            int i = t + (j << 10);
            float2 v = L[swz(i)];
            __half2 h = __floats2half2_rn(v.x * invn, v.y * invn);
            if (i < 8192) H0[i] = h; else H1[i - 8192] = h;
        }
    }
}

// ---------- Kernel 4: conv — FFT(x packed), multiply K-hat, inverse -------
template<int MODE>
__global__ __launch_bounds__(1024)
void conv_kernel(const float* __restrict__ x, const float2* __restrict__ KF,
                 float* __restrict__ out)
{
    __shared__ float2 L[NF];
    const int d = blockIdx.x, t = threadIdx.x;
    const float* x0 = x + (size_t)d * LSEQ;
    const float* x1 = x + (size_t)(DIMC + d) * LSEQ;
    float* o0 = out + (size_t)d * LSEQ;
    float* o1 = out + (size_t)(DIMC + d) * LSEQ;
#pragma unroll
    for (int j = 0; j < 8; ++j) {
        int n = t + (j << 10);
        L[swz(n)] = make_float2(x0[n], x1[n]);
    }
    FWD_ALL(L, t);
    __syncthreads();
    // NO extra scaling here: K-hat already carries the single required 1/N.
    if (MODE == 0) {
        const float2* Kd = KF + (size_t)d * NF;
#pragma unroll
        for (int j = 0; j < 16; ++j) {
            int i = t + (j << 10);
            float2 z = L[swz(i)];
            float2 k = Kd[i];
            L[swz(i)] = make_float2(z.x * k.x - z.y * k.y,
                                    z.x * k.y + z.y * k.x);
        }
    } else {
        const __half2* H0 = (const __half2*)(out + (size_t)d * LSEQ);
        const __half2* H1 = (const __half2*)(out + (size_t)(DIMC + d) * LSEQ);
#pragma unroll
        for (int j = 0; j < 16; ++j) {
            int i = t + (j << 10);
            float2 z = L[swz(i)];
            float2 k = __half22float2(i < 8192 ? H0[i] : H1[i - 8192]);
            L[swz(i)] = make_float2(z.x * k.x - z.y * k.y,
                                    z.x * k.y + z.y * k.x);
        }
    }
    inv_stage<0>(L, t); inv_stage<2>(L, t); inv_stage<4>(L, t);
    inv_stage<6>(L, t); inv_stage<8>(L, t); inv_stage<10>(L, t);
    inv_stage_last(L, t);
    __syncthreads();
#pragma unroll
    for (int j = 0; j < 8; ++j) {
        int n = t + (j << 10);
        float2 v = L[swz(n)];
        o0[n] = v.x;             // batch 0
        o1[n] = v.y;             // batch 1 (imag part of packed signal)
    }
}

extern "C" void kernel_launch(void* const* d_in, const int* in_sizes, int n_in,
                              void* d_out, int out_size, void* d_ws, size_t ws_size,
                              hipStream_t stream)
{
    (void)in_sizes; (void)n_in; (void)out_size;
    const float* x    = (const float*)d_in[0];
    const float* W0   = (const float*)d_in[1];
    const float* b0   = (const float*)d_in[2];
    const float* W1   = (const float*)d_in[3];
    const float* b1   = (const float*)d_in[4];
    const float* W2   = (const float*)d_in[5];
    const float* b2   = (const float*)d_in[6];
    const float* Wf   = (const float*)d_in[7];
    const float* freq = (const float*)d_in[8];
    const float* bias = (const float*)d_in[9];
    float* out = (float*)d_out;

    // Staging inside d_out:
    //   hws = out rows 0..63      (h2, consumed by filter before kfft/conv)
    //   kws = out + DIMC*LSEQ     (k rows == out rows DIMC..2*DIMC)
    float* hws = out;
    float* kws = out + (size_t)DIMC * LSEQ;

    hipLaunchKernelGGL(hidden_kernel, dim3(LSEQ / 4), dim3(256), 0, stream,
                       W0, b0, W1, b1, W2, b2, freq, hws);
    hipLaunchKernelGGL(filter_kernel, dim3(LSEQ / 256, DIMC / DCHUNK), dim3(256), 0, stream,
                       hws, Wf, kws);

    const size_t kbytes = (size_t)DIMC * NF * sizeof(float2);
    if (ws_size >= kbytes) {
        float2* KF = (float2*)d_ws;
        hipLaunchKernelGGL(kfft_kernel<0>, dim3(DIMC), dim3(1024), 0, stream,
                           kws, bias, KF, nullptr);
        hipLaunchKernelGGL(conv_kernel<0>, dim3(DIMC), dim3(1024), 0, stream,
                           x, KF, out);
    } else {
        hipLaunchKernelGGL(kfft_kernel<1>, dim3(DIMC), dim3(1024), 0, stream,
                           kws, bias, nullptr, out);
        hipLaunchKernelGGL(conv_kernel<1>, dim3(DIMC), dim3(1024), 0, stream,
                           x, nullptr, out);
    }
}

// Round 12
// 221.722 us; speedup vs baseline: 2.7790x; 1.4435x over previous
//
#include <hip/hip_runtime.h>
#include <hip/hip_fp16.h>

// HyenaFilter = implicit-filter MLP (tiny) + FFT convolution.
// fftconv (fft_size=16384 >= 2L) == causal linear conv; bias folded into k[0].
// R8/R9: LDS-resident radix-4 FFT (7 stages, N=16384), named scalars only.
// R10-R12: '#pragma unroll 1' on butterfly/multiply loops — R9 profile showed
//     all pipes <20% busy with wall 4x the pipe-sum => front-end stall;
//     fully-unrolled conv is ~38KB code > 32KB L1I. Rolled loops ~10KB.
//     (R12 = third submission: container died before measuring R10/R11.)

#define DIMC  768
#define BANDS 16
#define FO    64
#define LSEQ  8192
#define NF    16384
#define PI_F  3.14159265358979323846f

// bank-decorrelating swizzle for float2 LDS indices
__device__ __forceinline__ int swz(int i) { return i ^ ((i >> 4) & 15); }

// x * (c - i s)   [forward twiddle]
__device__ __forceinline__ float2 cmulm(float xr, float xi, float c, float s) {
    return make_float2(xr * c + xi * s, xi * c - xr * s);
}
// x * (c + i s)   [inverse twiddle]
__device__ __forceinline__ float2 cmulp(float xr, float xi, float c, float s) {
    return make_float2(xr * c - xi * s, xi * c + xr * s);
}

// ---- forward DIF radix-4 stage, quarter-stride S = 1<<SH -----------------
template<int SH>
__device__ __forceinline__ void fwd_stage(float2* L, int t)
{
    __syncthreads();
    const int S = 1 << SH;
#pragma unroll 1
    for (int m = 0; m < 4; ++m) {
        int b = t + (m << 10);
        int q = b & (S - 1);
        int p = ((b >> SH) << (SH + 2)) + q;
        float2 U0 = L[swz(p)];
        float2 U1 = L[swz(p + S)];
        float2 U2 = L[swz(p + 2 * S)];
        float2 U3 = L[swz(p + 3 * S)];
        float th = (float)q * (PI_F / (2.0f * (float)S));
        float c1 = __cosf(th), s1 = __sinf(th);
        float c2 = c1 * c1 - s1 * s1, s2 = 2.0f * c1 * s1;
        float c3 = c1 * c2 - s1 * s2, s3 = c1 * s2 + s1 * c2;
        float Ar = U0.x + U2.x, Ai = U0.y + U2.y;
        float Br = U0.x - U2.x, Bi = U0.y - U2.y;
        float Cr = U1.x + U3.x, Ci = U1.y + U3.y;
        float Dr = U1.y - U3.y, Di = U3.x - U1.x;     // D = -i(u1-u3)
        L[swz(p)]         = make_float2(Ar + Cr, Ai + Ci);
        L[swz(p + S)]     = cmulm(Br + Dr, Bi + Di, c1, s1);
        L[swz(p + 2 * S)] = cmulm(Ar - Cr, Ai - Ci, c2, s2);
        L[swz(p + 3 * S)] = cmulm(Br - Dr, Bi - Di, c3, s3);
    }
}

// first forward stage (S=4096) with zero-padded input: u2 = u3 = 0.
// Upper half of LDS is never read; it is fully written here.
__device__ __forceinline__ void fwd_stage_zp(float2* L, int t)
{
    __syncthreads();
#pragma unroll 1
    for (int m = 0; m < 4; ++m) {
        int b = t + (m << 10);
        float2 U0 = L[swz(b)];
        float2 U1 = L[swz(b + 4096)];
        float th = (float)b * (PI_F / 8192.0f);
        float c1 = __cosf(th), s1 = __sinf(th);
        float c2 = c1 * c1 - s1 * s1, s2 = 2.0f * c1 * s1;
        float c3 = c1 * c2 - s1 * s2, s3 = c1 * s2 + s1 * c2;
        // A=B=U0, C=U1, D=-i*U1=(U1.y, -U1.x)
        L[swz(b)]         = make_float2(U0.x + U1.x, U0.y + U1.y);
        L[swz(b + 4096)]  = cmulm(U0.x + U1.y, U0.y - U1.x, c1, s1);
        L[swz(b + 8192)]  = cmulm(U0.x - U1.x, U0.y - U1.y, c2, s2);
        L[swz(b + 12288)] = cmulm(U0.x - U1.y, U0.y + U1.x, c3, s3);
    }
}

// ---- inverse DIT radix-4 stage (consumes scrambled, conj twiddles) -------
template<int SH>
__device__ __forceinline__ void inv_stage(float2* L, int t)
{
    __syncthreads();
    const int S = 1 << SH;
#pragma unroll 1
    for (int m = 0; m < 4; ++m) {
        int b = t + (m << 10);
        int q = b & (S - 1);
        int p = ((b >> SH) << (SH + 2)) + q;
        float2 V0 = L[swz(p)];
        float2 V1 = L[swz(p + S)];
        float2 V2 = L[swz(p + 2 * S)];
        float2 V3 = L[swz(p + 3 * S)];
        float th = (float)q * (PI_F / (2.0f * (float)S));
        float c1 = __cosf(th), s1 = __sinf(th);
        float c2 = c1 * c1 - s1 * s1, s2 = 2.0f * c1 * s1;
        float c3 = c1 * c2 - s1 * s2, s3 = c1 * s2 + s1 * c2;
        V1 = cmulp(V1.x, V1.y, c1, s1);
        V2 = cmulp(V2.x, V2.y, c2, s2);
        V3 = cmulp(V3.x, V3.y, c3, s3);
        float e0r = V0.x + V2.x, e0i = V0.y + V2.y;
        float e1r = V0.x - V2.x, e1i = V0.y - V2.y;
        float f0r = V1.x + V3.x, f0i = V1.y + V3.y;
        float f1r = V1.x - V3.x, f1i = V1.y - V3.y;   // i*f1 = (-f1i, f1r)
        L[swz(p)]         = make_float2(e0r + f0r, e0i + f0i);
        L[swz(p + S)]     = make_float2(e1r - f1i, e1i + f1r);
        L[swz(p + 2 * S)] = make_float2(e0r - f0r, e0i - f0i);
        L[swz(p + 3 * S)] = make_float2(e1r + f1i, e1i - f1r);
    }
}

// last inverse stage (S=4096), truncated: only outputs n < 8192 are needed.
__device__ __forceinline__ void inv_stage_last(float2* L, int t)
{
    __syncthreads();
#pragma unroll 1
    for (int m = 0; m < 4; ++m) {
        int b = t + (m << 10);     // p = q = b
        float2 V0 = L[swz(b)];
        float2 V1 = L[swz(b + 4096)];
        float2 V2 = L[swz(b + 8192)];
        float2 V3 = L[swz(b + 12288)];
        float th = (float)b * (PI_F / 8192.0f);
        float c1 = __cosf(th), s1 = __sinf(th);
        float c2 = c1 * c1 - s1 * s1, s2 = 2.0f * c1 * s1;
        float c3 = c1 * c2 - s1 * s2, s3 = c1 * s2 + s1 * c2;
        V1 = cmulp(V1.x, V1.y, c1, s1);
        V2 = cmulp(V2.x, V2.y, c2, s2);
        V3 = cmulp(V3.x, V3.y, c3, s3);
        float e1r = V0.x - V2.x, e1i = V0.y - V2.y;
        float f1r = V1.x - V3.x, f1i = V1.y - V3.y;
        L[swz(b)]        = make_float2(V0.x + V2.x + V1.x + V3.x,
                                       V0.y + V2.y + V1.y + V3.y);
        L[swz(b + 4096)] = make_float2(e1r - f1i, e1i + f1r);
    }
}

#define FWD_ALL(L, t)  do { fwd_stage_zp(L, t); fwd_stage<10>(L, t); \
    fwd_stage<8>(L, t); fwd_stage<6>(L, t); fwd_stage<4>(L, t); \
    fwd_stage<2>(L, t); fwd_stage<0>(L, t); } while (0)

// ---------- Kernel 1: MLP hidden states h2[FO][LSEQ] ----------------------
__global__ void hidden_kernel(const float* __restrict__ W0, const float* __restrict__ b0,
                              const float* __restrict__ W1, const float* __restrict__ b1,
                              const float* __restrict__ W2, const float* __restrict__ b2,
                              const float* __restrict__ freq, float* __restrict__ hws)
{
    const int lane = threadIdx.x & 63;
    const int p = blockIdx.x * (blockDim.x >> 6) + (threadIdx.x >> 6);
    if (p >= LSEQ) return;
    const float tt = (float)p / (float)(LSEQ - 1);
    const float w  = 6.283185307179586f * (float)p / (float)LSEQ;

    float acc = b0[lane] + tt * W0[lane];
#pragma unroll
    for (int j = 0; j < BANDS; ++j) {
        float f = 1e-4f + (float)j * ((15.0f - 1e-4f) / 15.0f);
        float a = f * w;
        acc += __cosf(a)  * W0[(1 + j) * FO + lane];
        acc += -__sinf(a) * W0[(1 + BANDS + j) * FO + lane];
    }
    float h = __sinf(freq[lane] * acc);

    acc = b1[lane];
#pragma unroll
    for (int e = 0; e < FO; ++e) acc += __shfl(h, e) * W1[e * FO + lane];
    float h1 = __sinf(freq[lane] * acc);

    acc = b2[lane];
#pragma unroll
    for (int e = 0; e < FO; ++e) acc += __shfl(h1, e) * W2[e * FO + lane];
    float h2 = __sinf(freq[lane] * acc);

    hws[lane * LSEQ + p] = h2;    // feature-major, coalesced
}

// ---------- Kernel 2: k[d][p] = (h2 . Wf) * (exp(-t|delta|)+0.05) ---------
#define DCHUNK 96
__global__ __launch_bounds__(256)
void filter_kernel(const float* __restrict__ hws, const float* __restrict__ Wf,
                   float* __restrict__ kws)
{
    __shared__ float hsh[256][65];   // stride 65: conflict-free
    const int tid = threadIdx.x;
    const int p  = blockIdx.x * 256 + tid;
    const int d0 = blockIdx.y * DCHUNK;
#pragma unroll
    for (int j = 0; j < FO; ++j) hsh[tid][j] = hws[j * LSEQ + p];  // coalesced
    __syncthreads();
    const float tt = (float)p / (float)(LSEQ - 1);
    const float min_decay = -3.0701134573253937f;   // ln(0.01)/1.5
    const float max_decay = -15.350567286626971f;   // ln(0.01)/0.3
    for (int dd = 0; dd < DCHUNK; ++dd) {
        const int d = d0 + dd;
        float acc = 0.f;
#pragma unroll
        for (int j = 0; j < FO; ++j) acc += hsh[tid][j] * Wf[j * DIMC + d];
        float delta = min_decay + (max_decay - min_decay) * ((float)d / (float)(DIMC - 1));
        float dec = __expf(-tt * fabsf(delta));
        kws[(size_t)d * LSEQ + p] = acc * (dec + 0.05f);
    }
}

// ---------- Kernel 3: K-hat = FFT(k)/N per channel ------------------------
// MODE 0: fp32 into d_ws. MODE 1: half2 overlaid on out rows (d, DIMC+d),
// which this block fully reads (kws row d == out row DIMC+d) before writing.
template<int MODE>
__global__ __launch_bounds__(1024)
void kfft_kernel(const float* __restrict__ kf, const float* __restrict__ bias,
                 float2* __restrict__ KF, float* __restrict__ outbase)
{
    __shared__ float2 L[NF];
    const int d = blockIdx.x, t = threadIdx.x;
    const float* krow = kf + (size_t)d * LSEQ;
#pragma unroll
    for (int j = 0; j < 8; ++j) {
        int n = t + (j << 10);
        float v = krow[n];
        if (n == 0) v += bias[d];          // delta at s=0 == +bias*u term
        L[swz(n)] = make_float2(v, 0.f);
    }
    FWD_ALL(L, t);
    __syncthreads();
    const float invn = 1.0f / 16384.0f;    // the ONLY 1/N in the pipeline
    if (MODE == 0) {
        float2* Kd = KF + (size_t)d * NF;
#pragma unroll 1
        for (int j = 0; j < 16; ++j) {
            int i = t + (j << 10);
            float2 v = L[swz(i)];
            Kd[i] = make_float2(v.x * invn, v.y * invn);
        }
    } else {
        __half2* H0 = (__half2*)(outbase + (size_t)d * LSEQ);
        __half2* H1 = (__half2*)(outbase + (size_t)(DIMC + d) * LSEQ);
#pragma unroll 1
        for (int j = 0; j < 16; ++j) {
            int i = t + (j << 10);
            float2 v = L[swz(i)];
            __half2 h = __floats2half2_rn(v.x * invn, v.y * invn);
            if (i < 8192) H0[i] = h; else H1[i - 8192] = h;
        }
    }
}

// ---------- Kernel 4: conv — FFT(x packed), multiply K-hat, inverse -------
template<int MODE>
__global__ __launch_bounds__(1024)
void conv_kernel(const float* __restrict__ x, const float2* __restrict__ KF,
                 float* __restrict__ out)
{
    __shared__ float2 L[NF];
    const int d = blockIdx.x, t = threadIdx.x;
    const float* x0 = x + (size_t)d * LSEQ;
    const float* x1 = x + (size_t)(DIMC + d) * LSEQ;
    float* o0 = out + (size_t)d * LSEQ;
    float* o1 = out + (size_t)(DIMC + d) * LSEQ;
#pragma unroll
    for (int j = 0; j < 8; ++j) {
        int n = t + (j << 10);
        L[swz(n)] = make_float2(x0[n], x1[n]);
    }
    FWD_ALL(L, t);
    __syncthreads();
    // NO extra scaling here: K-hat already carries the single required 1/N.
    if (MODE == 0) {
        const float2* Kd = KF + (size_t)d * NF;
#pragma unroll 1
        for (int j = 0; j < 16; ++j) {
            int i = t + (j << 10);
            float2 z = L[swz(i)];
            float2 k = Kd[i];
            L[swz(i)] = make_float2(z.x * k.x - z.y * k.y,
                                    z.x * k.y + z.y * k.x);
        }
    } else {
        const __half2* H0 = (const __half2*)(out + (size_t)d * LSEQ);
        const __half2* H1 = (const __half2*)(out + (size_t)(DIMC + d) * LSEQ);
#pragma unroll 1
        for (int j = 0; j < 16; ++j) {
            int i = t + (j << 10);
            float2 z = L[swz(i)];
            float2 k = __half22float2(i < 8192 ? H0[i] : H1[i - 8192]);
            L[swz(i)] = make_float2(z.x * k.x - z.y * k.y,
                                    z.x * k.y + z.y * k.x);
        }
    }
    inv_stage<0>(L, t); inv_stage<2>(L, t); inv_stage<4>(L, t);
    inv_stage<6>(L, t); inv_stage<8>(L, t); inv_stage<10>(L, t);
    inv_stage_last(L, t);
    __syncthreads();
#pragma unroll
    for (int j = 0; j < 8; ++j) {
        int n = t + (j << 10);
        float2 v = L[swz(n)];
        o0[n] = v.x;             // batch 0
        o1[n] = v.y;             // batch 1 (imag part of packed signal)
    }
}

extern "C" void kernel_launch(void* const* d_in, const int* in_sizes, int n_in,
                              void* d_out, int out_size, void* d_ws, size_t ws_size,
                              hipStream_t stream)
{
    (void)in_sizes; (void)n_in; (void)out_size;
    const float* x    = (const float*)d_in[0];
    const float* W0   = (const float*)d_in[1];
    const float* b0   = (const float*)d_in[2];
    const float* W1   = (const float*)d_in[3];
    const float* b1   = (const float*)d_in[4];
    const float* W2   = (const float*)d_in[5];
    const float* b2   = (const float*)d_in[6];
    const float* Wf   = (const float*)d_in[7];
    const float* freq = (const float*)d_in[8];
    const float* bias = (const float*)d_in[9];
    float* out = (float*)d_out;

    // Staging inside d_out:
    //   hws = out rows 0..63      (h2, consumed by filter before kfft/conv)
    //   kws = out + DIMC*LSEQ     (k rows == out rows DIMC..2*DIMC)
    float* hws = out;
    float* kws = out + (size_t)DIMC * LSEQ;

    hipLaunchKernelGGL(hidden_kernel, dim3(LSEQ / 4), dim3(256), 0, stream,
                       W0, b0, W1, b1, W2, b2, freq, hws);
    hipLaunchKernelGGL(filter_kernel, dim3(LSEQ / 256, DIMC / DCHUNK), dim3(256), 0, stream,
                       hws, Wf, kws);

    const size_t kbytes = (size_t)DIMC * NF * sizeof(float2);
    if (ws_size >= kbytes) {
        float2* KF = (float2*)d_ws;
        hipLaunchKernelGGL(kfft_kernel<0>, dim3(DIMC), dim3(1024), 0, stream,
                           kws, bias, KF, nullptr);
        hipLaunchKernelGGL(conv_kernel<0>, dim3(DIMC), dim3(1024), 0, stream,
                           x, KF, out);
    } else {
        hipLaunchKernelGGL(kfft_kernel<1>, dim3(DIMC), dim3(1024), 0, stream,
                           kws, bias, nullptr, out);
        hipLaunchKernelGGL(conv_kernel<1>, dim3(DIMC), dim3(1024), 0, stream,
                           x, nullptr, out);
    }
}